// Round 6
// baseline (184.333 us; speedup 1.0000x reference)
//
#include <hip/hip_runtime.h>
#include <hip/hip_bf16.h>
#include <math.h>

typedef __attribute__((ext_vector_type(8))) __bf16 bf16x8;
typedef __attribute__((ext_vector_type(4))) float f32x4;

#define PAIRF 260  // floats per 2-row pair: 256 + 4 pad -> frag reads are 2-way bank-aliased (free)

__device__ __forceinline__ float sigmoid_f(float v) {
  return __builtin_amdgcn_rcpf(1.f + __expf(-v));
}
__device__ __forceinline__ float tanh_f(float z) {
  float az = fabsf(z);
  float e = __expf(-2.f * az);
  float t = (1.f - e) * __builtin_amdgcn_rcpf(1.f + e);
  return copysignf(t, z);
}
__device__ __forceinline__ bf16x8 cvt8(float4 a, float4 b) {
  bf16x8 r;
  r[0] = (__bf16)a.x; r[1] = (__bf16)a.y; r[2] = (__bf16)a.z; r[3] = (__bf16)a.w;
  r[4] = (__bf16)b.x; r[5] = (__bf16)b.y; r[6] = (__bf16)b.z; r[7] = (__bf16)b.w;
  return r;
}
// Async global->LDS DMA, 16 B/lane. lds dest must be wave-uniform; each lane's
// 16 B lands at base + lane*16 (m97-proven staging path).
__device__ __forceinline__ void gl_lds16(const float* g, float* l) {
  __builtin_amdgcn_global_load_lds((const __attribute__((address_space(1))) void*)g,
                                   (__attribute__((address_space(3))) void*)l, 16, 0, 0);
}

// Block = 512 thr = 8 waves; wave w owns output cols [16w,16w+16) with weights
// persistent in 48 VGPRs -> full-row blocks (compulsory reads, full-line writes).
// x/h staged as RAW fp32 via global_load_lds into a double buffer, issued one
// 32-row interval ahead (DMA completes under compute; barrier drain ~free).
// fp32 h tile in LDS doubles as exact h0 for the epilogue. One barrier/interval.
__global__ __launch_bounds__(512, 4) void augru_kernel(
    const float* __restrict__ x, const float* __restrict__ hp,
    const float* __restrict__ att,
    const float* __restrict__ Wx, const float* __restrict__ bx,
    const float* __restrict__ Wh, const float* __restrict__ bh,
    float* __restrict__ out) {
  __shared__ float lds[2][2][16 * PAIRF];  // [buf][mat x/h][pair(2 rows)+pad] = 66,560 B

  const int tid  = threadIdx.x;
  const int wave = tid >> 6;
  const int lane = tid & 63;
  const int quad = lane >> 4;
  const int l15  = lane & 15;
  const int col  = wave * 16 + l15;

  // ---- persistent B-fragments (proven layout): m = gate*2 + (0:Wx,1:Wh)
  bf16x8 wf[6][4];
#pragma unroll
  for (int m = 0; m < 6; ++m) {
    const float* src = (m & 1) ? Wh : Wx;
    const float* wr  = src + ((m >> 1) * 128 + col) * 128 + quad * 8;
#pragma unroll
    for (int kt = 0; kt < 4; ++kt)
      wf[m][kt] = cvt8(*(const float4*)(wr + kt * 32), *(const float4*)(wr + kt * 32 + 4));
  }
  const float bu_  = bx[col] + bh[col];
  const float br_  = bx[128 + col] + bh[128 + col];
  const float bxh_ = bx[256 + col];
  const float bhh_ = bh[256 + col];

  const int T  = 4;                       // 32-row intervals per block
  const int r0 = blockIdx.x * 128;        // 512 blocks x 128 rows = 65536

  // stage interval 0 into buf 0: per wave 2 DMA instrs per mat (pairs w, w+8)
  auto stage = [&](int buf, int rb) {
    gl_lds16(x  + (size_t)(rb + 2 * wave) * 128      + lane * 4, &lds[buf][0][wave * PAIRF]);
    gl_lds16(x  + (size_t)(rb + 2 * (wave + 8)) * 128 + lane * 4, &lds[buf][0][(wave + 8) * PAIRF]);
    gl_lds16(hp + (size_t)(rb + 2 * wave) * 128      + lane * 4, &lds[buf][1][wave * PAIRF]);
    gl_lds16(hp + (size_t)(rb + 2 * (wave + 8)) * 128 + lane * 4, &lds[buf][1][(wave + 8) * PAIRF]);
  };

  stage(0, r0);
  __syncthreads();  // one-time full DMA wait

  for (int t = 0; t < T; ++t) {
    const int b  = t & 1;
    const int rb = r0 + t * 32;

    // att for this interval FIRST (so its vmcnt wait can't drain the DMA below)
    float4 attv[2];
#pragma unroll
    for (int n = 0; n < 2; ++n)
      attv[n] = *(const float4*)(att + rb + n * 16 + quad * 4);

    // async-stage next interval into the other buffer (in flight under compute)
    if (t + 1 < T) stage(b ^ 1, rb + 32);

    // ---- 2 sub-tiles of 16 rows
#pragma unroll
    for (int n = 0; n < 2; ++n) {
      // A-fragments from fp32 LDS: row = 16n + l15
      const int pr  = 8 * n + (l15 >> 1);
      const int odd = l15 & 1;
      const float* xrow = &lds[b][0][pr * PAIRF + odd * 128];
      const float* hrow = &lds[b][1][pr * PAIRF + odd * 128];
      bf16x8 xf[4], hf[4];
#pragma unroll
      for (int kt = 0; kt < 4; ++kt) {
        const int o = kt * 32 + quad * 8;
        xf[kt] = cvt8(*(const float4*)(xrow + o), *(const float4*)(xrow + o + 4));
        hf[kt] = cvt8(*(const float4*)(hrow + o), *(const float4*)(hrow + o + 4));
      }

      f32x4 aU = (f32x4)0.f, aR = (f32x4)0.f, aHX = (f32x4)0.f, aHH = (f32x4)0.f;
#pragma unroll
      for (int kt = 0; kt < 4; ++kt) {
        aU  = __builtin_amdgcn_mfma_f32_16x16x32_bf16(xf[kt], wf[0][kt], aU, 0, 0, 0);
        aU  = __builtin_amdgcn_mfma_f32_16x16x32_bf16(hf[kt], wf[1][kt], aU, 0, 0, 0);
        aR  = __builtin_amdgcn_mfma_f32_16x16x32_bf16(xf[kt], wf[2][kt], aR, 0, 0, 0);
        aR  = __builtin_amdgcn_mfma_f32_16x16x32_bf16(hf[kt], wf[3][kt], aR, 0, 0, 0);
        aHX = __builtin_amdgcn_mfma_f32_16x16x32_bf16(xf[kt], wf[4][kt], aHX, 0, 0, 0);
        aHH = __builtin_amdgcn_mfma_f32_16x16x32_bf16(hf[kt], wf[5][kt], aHH, 0, 0, 0);
      }

      // ---- epilogue: h0 exact fp32 from LDS; C layout col=l15, row=quad*4+rr
      const float* ap = (const float*)&attv[n];
#pragma unroll
      for (int rr = 0; rr < 4; ++rr) {
        const int rl = 16 * n + quad * 4 + rr;           // row within interval
        const float h0 = lds[b][1][(rl >> 1) * PAIRF + (rl & 1) * 128 + col];
        float u  = sigmoid_f(aU[rr] + bu_);
        float r  = sigmoid_f(aR[rr] + br_);
        float ht = tanh_f(aHX[rr] + bxh_ + r * (aHH[rr] + bhh_));
        float ua = ap[rr] * u;
        out[(size_t)(rb + rl) * 128 + col] = fmaf(ua, ht - h0, h0);
      }
    }

    __syncthreads();  // drains next-interval DMA (long in flight) + store acks
  }
}

extern "C" void kernel_launch(void* const* d_in, const int* in_sizes, int n_in,
                              void* d_out, int out_size, void* d_ws, size_t ws_size,
                              hipStream_t stream) {
  const float* x   = (const float*)d_in[0];
  const float* hpv = (const float*)d_in[1];
  const float* att = (const float*)d_in[2];
  const float* Wx  = (const float*)d_in[3];
  const float* bx  = (const float*)d_in[4];
  const float* Wh  = (const float*)d_in[5];
  const float* bh  = (const float*)d_in[6];
  float* out = (float*)d_out;

  augru_kernel<<<512, 512, 0, stream>>>(x, hpv, att, Wx, bx, Wh, bh, out);
}